// Round 7
// baseline (847.719 us; speedup 1.0000x reference)
//
#include <hip/hip_runtime.h>
#include <hip/hip_bf16.h>
#include <math.h>

// GETS calibrator: MoE-GCN. N nodes, E edges, C=64, F=512, FH=32, DH=16.
// R7: (a) k_proj per-block K-rotation to desync the shared W scalar stream
//     (R6 showed VALUBusy ~ 1 wave/SIMD: K$-miss convoy across waves).
//     (b) FG folded to cfg[3] inside k_proj (FG buffer eliminated; gating math
//     still exact two-step fp32 -> top-k decisions unchanged).

#define XD 160   // aggregated feature dim
#define CC 64    // classes

static __device__ inline unsigned pk_bf16(float a, float b) {
  __hip_bfloat162 h;
  h.x = __float2bfloat16(a);
  h.y = __float2bfloat16(b);
  return *reinterpret_cast<unsigned*>(&h);
}
static __device__ inline float bf_lo(unsigned u) {
  unsigned v = u << 16;
  return __builtin_bit_cast(float, v);
}
static __device__ inline float bf_hi(unsigned u) {
  unsigned v = u & 0xffff0000u;
  return __builtin_bit_cast(float, v);
}

// ---------------- degree counting ----------------
__global__ void k_degrees(const int* __restrict__ ei, int E,
                          int* __restrict__ deg_i, int* __restrict__ deg_dst) {
  int e = blockIdx.x * blockDim.x + threadIdx.x;
  if (e >= E) return;
  int s = ei[e], d = ei[E + e];
  atomicAdd(&deg_i[s], 1);
  atomicAdd(&deg_i[d], 1);
  atomicAdd(&deg_dst[d], 1);
}

// ---------------- 2-level exclusive scan of deg_dst -> row_start ----------------
__global__ void k_scan1(const int* __restrict__ deg, int n, int* __restrict__ bsum) {
  __shared__ int red[1024];
  int tid = threadIdx.x;
  int i = blockIdx.x * 1024 + tid;
  red[tid] = (i < n) ? deg[i] : 0;
  __syncthreads();
  for (int s = 512; s > 0; s >>= 1) {
    if (tid < s) red[tid] += red[tid + s];
    __syncthreads();
  }
  if (tid == 0) bsum[blockIdx.x] = red[0];
}

__global__ void k_scan2(int* __restrict__ bsum, int nb, int* __restrict__ row_start, int n) {
  if (threadIdx.x == 0 && blockIdx.x == 0) {
    int run = 0;
    for (int b = 0; b < nb; ++b) { int t = bsum[b]; bsum[b] = run; run += t; }
    row_start[n] = run;   // == E
  }
}

__global__ void k_scan3(const int* __restrict__ deg, int n, const int* __restrict__ bsum,
                        int* __restrict__ row_start, float* __restrict__ dinv) {
  __shared__ int sc[1024];
  int tid = threadIdx.x;
  int i = blockIdx.x * 1024 + tid;
  int v = (i < n) ? deg[i] : 0;
  sc[tid] = v;
  __syncthreads();
  for (int ofs = 1; ofs < 1024; ofs <<= 1) {
    int t = (tid >= ofs) ? sc[tid - ofs] : 0;
    __syncthreads();
    sc[tid] += t;
    __syncthreads();
  }
  if (i < n) {
    int incl = sc[tid];
    row_start[i] = incl - v + bsum[blockIdx.x];
    dinv[i] = rsqrtf((float)v + 1.0f);   // GCN deg = indeg + 1 (self loop)
  }
}

// ---------------- CSR fill (src + precomputed coef per edge) ----------------
__global__ void k_fill(const int* __restrict__ ei, int E, const int* __restrict__ row_start,
                       int* __restrict__ cursor, const float* __restrict__ dinv,
                       int* __restrict__ srcs, float* __restrict__ coefs) {
  int e = blockIdx.x * blockDim.x + threadIdx.x;
  if (e >= E) return;
  int s = ei[e], d = ei[E + e];
  int pos = row_start[d] + atomicAdd(&cursor[d], 1);
  srcs[pos] = s;
  coefs[pos] = dinv[s] * dinv[d];
}

// ---------------- projection: feat(n,512) @ {Wf0,Wf2,Wfg}(512,32) ----------------
// lane = node, wave m = matrix, W via uniform s_load, zero LDS.
// Per-block K-rotation desyncs the W stream across blocks (K$ convoy breaker).
// m==2 folds FG into cfg[3] = (feat@Wfg + bfg) . wg[64:96] and stores 3 floats.
__global__ __launch_bounds__(192) void k_proj(
    const float* __restrict__ feat,
    const float* __restrict__ Wf0, const float* __restrict__ bf0,
    const float* __restrict__ Wf2, const float* __restrict__ bf2,
    const float* __restrict__ Wfg, const float* __restrict__ bfg,
    const float* __restrict__ wg,
    unsigned* __restrict__ Xu, float* __restrict__ CFG, int n) {
  int l = threadIdx.x & 63;
  int m = __builtin_amdgcn_readfirstlane(threadIdx.x >> 6);   // wave-uniform matrix id
  int node = blockIdx.x * 64 + l;
  int nc = node < n ? node : n - 1;
  const float* fr = feat + (size_t)nc * 512;

  const float* Wm;
  const float* bm;
  if (m == 0)      { Wm = Wf0; bm = bf0; }
  else if (m == 1) { Wm = Wf2; bm = bf2; }
  else             { Wm = Wfg; bm = bfg; }

  float acc[32];
#pragma unroll
  for (int c = 0; c < 32; ++c) acc[c] = 0.f;

  int s0 = (blockIdx.x & 7) << 4;   // rotate start: 0,16,...,112 (x4 floats = 256B steps)
  for (int t = 0; t < 128; ++t) {
    int kq = (t + s0) & 127;
    float4 f4 = *(const float4*)&fr[kq * 4];
    const float* p = (const float*)&f4;
#pragma unroll
    for (int j = 0; j < 4; ++j) {
      float fv = p[j];
      const float* wr = Wm + (kq * 4 + j) * 32;   // uniform address -> s_load
#pragma unroll
      for (int c = 0; c < 32; ++c) acc[c] += fv * wr[c];
    }
  }

  if (node < n) {
    if (m == 2) {
      // fold: cfg[e] = sum_j (acc[j]+bfg[j]) * wg[(64+j)*3+e]   (exact fp32 two-step)
      float cf0 = 0.f, cf1 = 0.f, cf2 = 0.f;
#pragma unroll
      for (int j = 0; j < 32; ++j) {
        float v = acc[j] + bm[j];
        cf0 += v * wg[(64 + j) * 3 + 0];
        cf1 += v * wg[(64 + j) * 3 + 1];
        cf2 += v * wg[(64 + j) * 3 + 2];
      }
      CFG[node] = cf0;
      CFG[n + node] = cf1;
      CFG[2 * (size_t)n + node] = cf2;
    } else {
      float ov[32];
#pragma unroll
      for (int c = 0; c < 32; ++c) ov[c] = acc[c] + bm[c];
      // bf16 pack: 32 vals -> 16 uints -> 4x uint4
      unsigned pk[16];
#pragma unroll
      for (int q = 0; q < 16; ++q) pk[q] = pk_bf16(ov[2 * q], ov[2 * q + 1]);
      // f0 -> features 64..95 (uint idx 32), f2 -> 112..143 (uint idx 56)
      unsigned* dst = Xu + (size_t)node * 80 + (m == 0 ? 32 : 56);
#pragma unroll
      for (int q = 0; q < 4; ++q)
        *(uint4*)&dst[q * 4] = *(const uint4*)&pk[q * 4];
    }
  }
}

// ---------------- build X (bf16): logits copy + degree embeddings ----------------
__global__ void k_buildx(const float* __restrict__ logits, const int* __restrict__ deg_i,
                         const float* __restrict__ Emb1, const float* __restrict__ Emb2,
                         unsigned* __restrict__ Xu, int n) {
  int gid = blockIdx.x * blockDim.x + threadIdx.x;
  if (gid >= n * 32) return;
  int node = gid >> 5, p = gid & 31;
  unsigned* xr = Xu + (size_t)node * 80;
  const float* lgr = logits + (size_t)node * 64;
  float2 lg = *(const float2*)&lgr[2 * p];
  xr[p] = pk_bf16(lg.x, lg.y);          // features 0..63 -> uint 0..31
  if (p < 8) {
    int dg = deg_i[node]; if (dg > 127) dg = 127;
    float2 e1 = *(const float2*)&Emb1[dg * 16 + 2 * p];
    float2 e2 = *(const float2*)&Emb2[dg * 16 + 2 * p];
    xr[48 + p] = pk_bf16(e1.x, e1.y);   // features 96..111
    xr[72 + p] = pk_bf16(e2.x, e2.y);   // features 144..159
  }
}

// ---------------- aggregation: Zt(bf16) = A_hat @ X(bf16), chunk-major ----------------
__global__ __launch_bounds__(256) void k_agg(
    const unsigned* __restrict__ Xu, unsigned* __restrict__ Ztu,
    const int* __restrict__ row_start, const int* __restrict__ srcs,
    const float* __restrict__ coefs, const float* __restrict__ dinv, int n) {
  int w = threadIdx.x >> 6, l = threadIdx.x & 63;
  int node = blockIdx.x * 4 + w;
  if (node >= n) return;
  int beg = row_start[node], end = row_start[node + 1];
  float ax = 0.f, ay = 0.f, bx = 0.f, by = 0.f;
  for (int i = beg; i < end; ++i) {
    int s = srcs[i];
    float c = coefs[i];
    const unsigned* xr = Xu + (size_t)s * 80;
    unsigned u = xr[l];
    ax += c * bf_lo(u);
    ay += c * bf_hi(u);
    if (l < 16) {
      unsigned u2 = xr[64 + l];
      bx += c * bf_lo(u2);
      by += c * bf_hi(u2);
    }
  }
  float di = dinv[node];
  float c2 = di * di;
  const unsigned* xs = Xu + (size_t)node * 80;
  {
    unsigned u = xs[l];
    ax += c2 * bf_lo(u);
    ay += c2 * bf_hi(u);
    if (l < 16) {
      unsigned u2 = xs[64 + l];
      bx += c2 * bf_lo(u2);
      by += c2 * bf_hi(u2);
    }
  }
  Ztu[2 * ((size_t)(l >> 1) * n + node) + (l & 1)] = pk_bf16(ax, ay);
  if (l < 16)
    Ztu[2 * ((size_t)(32 + (l >> 1)) * n + node) + (l & 1)] = pk_bf16(bx, by);
}

// ---------------- final: lane=node, W via uniform scalar loads, comb[64] in VGPRs ---------
__global__ __launch_bounds__(256, 4) void k_final(
    const unsigned* __restrict__ Ztu, const float* __restrict__ logits,
    const float* __restrict__ CFG, const int* __restrict__ deg_i,
    const float* __restrict__ W0, const float* __restrict__ b0,
    const float* __restrict__ W1, const float* __restrict__ b1,
    const float* __restrict__ W2, const float* __restrict__ b2,
    const float* __restrict__ Embg, const float* __restrict__ wg,
    float* __restrict__ out, int n) {
  int l = threadIdx.x & 63;
  int w = threadIdx.x >> 6;
  int g = blockIdx.x * 4 + w;
  int node = g * 64 + l;
  int nc = node < n ? node : n - 1;

  // ---- gating (fp32): logits part + Embg part + folded FG part ----
  float c0 = 0.f, c1 = 0.f, c2 = 0.f;
  const float* lgr = logits + (size_t)nc * 64;
#pragma unroll
  for (int q = 0; q < 16; ++q) {
    float4 v = *(const float4*)&lgr[q * 4];
    const float* p = (const float*)&v;
#pragma unroll
    for (int j = 0; j < 4; ++j) {
      int k = q * 4 + j;
      c0 += p[j] * wg[k * 3 + 0];
      c1 += p[j] * wg[k * 3 + 1];
      c2 += p[j] * wg[k * 3 + 2];
    }
  }
  {
    int dg = deg_i[nc]; if (dg > 127) dg = 127;
    const float* egr = Embg + dg * 16;
#pragma unroll
    for (int q = 0; q < 4; ++q) {
      float4 v = *(const float4*)&egr[q * 4];
      const float* p = (const float*)&v;
#pragma unroll
      for (int j = 0; j < 4; ++j) {
        int k = 96 + q * 4 + j;
        c0 += p[j] * wg[k * 3 + 0];
        c1 += p[j] * wg[k * 3 + 1];
        c2 += p[j] * wg[k * 3 + 2];
      }
    }
  }
  c0 += CFG[nc];
  c1 += CFG[n + nc];
  c2 += CFG[2 * (size_t)n + nc];

  int i0 = 0; float t0 = c0;
  if (c1 > t0) { t0 = c1; i0 = 1; }
  if (c2 > t0) { t0 = c2; i0 = 2; }
  float t1 = -3.4e38f; int i1 = 0;
  if (i0 != 0) { t1 = c0; i1 = 0; }
  if (i0 != 1 && c1 > t1) { t1 = c1; i1 = 1; }
  if (i0 != 2 && c2 > t1) { t1 = c2; i1 = 2; }
  float e1v = expf(t1 - t0);
  float gsum = 1.0f + e1v;
  float gA = 1.0f / gsum, gB = e1v / gsum;
  float g0 = (i0 == 0) ? gA : (i1 == 0) ? gB : 0.f;
  float g1 = (i0 == 1) ? gA : (i1 == 1) ? gB : 0.f;
  float g2 = (i0 == 2) ? gA : (i1 == 2) ? gB : 0.f;

  float comb[64];
#pragma unroll
  for (int c = 0; c < 64; ++c) comb[c] = 0.f;

#define CHUNK(CIDX, GE, WPTR, KROW)                                        \
  {                                                                        \
    uint2 zu = *(const uint2*)&Ztu[2 * ((size_t)(CIDX) * n + nc)];         \
    float zs[4] = {(GE) * bf_lo(zu.x), (GE) * bf_hi(zu.x),                 \
                   (GE) * bf_lo(zu.y), (GE) * bf_hi(zu.y)};                \
    const float* wr = (WPTR) + (KROW) * 64;                                \
    _Pragma("unroll") for (int kk = 0; kk < 4; ++kk) {                     \
      float zz = zs[kk];                                                   \
      const float* wrow = wr + kk * 64;                                    \
      _Pragma("unroll") for (int c = 0; c < 64; ++c)                       \
        comb[c] += zz * wrow[c];                                           \
    }                                                                      \
  }

  for (int t = 0; t < 24; ++t) CHUNK(t, g0, W0, 4 * t);
  for (int t = 0; t < 16; ++t) CHUNK(t, g1, W1, 4 * t);
  for (int t = 0; t < 4; ++t)  CHUNK(24 + t, g1, W1, 64 + 4 * t);
  for (int t = 0; t < 12; ++t) CHUNK(28 + t, g2, W2, 4 * t);
#undef CHUNK

#pragma unroll
  for (int c = 0; c < 64; ++c)
    comb[c] += g0 * b0[c] + g1 * b1[c] + g2 * b2[c];

  if (node < n) {
    float4* outr = (float4*)(out + (size_t)node * 64);
#pragma unroll
    for (int q = 0; q < 16; ++q) {
      float4 lg4 = *(const float4*)&lgr[q * 4];
      const float* pl = (const float*)&lg4;
      float4 o;
      float* po = (float*)&o;
#pragma unroll
      for (int j = 0; j < 4; ++j) {
        float v = comb[q * 4 + j];
        float sp = fmaxf(v, 0.f) + log1pf(expf(-fabsf(v)));
        po[j] = pl[j] * sp;
      }
      outr[q] = o;
    }
  }
}

extern "C" void kernel_launch(void* const* d_in, const int* in_sizes, int n_in,
                              void* d_out, int out_size, void* d_ws, size_t ws_size,
                              hipStream_t stream) {
  const float* logits = (const float*)d_in[0];
  const float* feat   = (const float*)d_in[1];
  const int*   ei     = (const int*)d_in[2];
  const float* Wf0 = (const float*)d_in[3];
  const float* bf0 = (const float*)d_in[4];
  const float* W0  = (const float*)d_in[5];
  const float* b0  = (const float*)d_in[6];
  const float* Emb1= (const float*)d_in[7];
  const float* W1  = (const float*)d_in[8];
  const float* b1  = (const float*)d_in[9];
  const float* Wf2 = (const float*)d_in[10];
  const float* bf2 = (const float*)d_in[11];
  const float* Emb2= (const float*)d_in[12];
  const float* W2  = (const float*)d_in[13];
  const float* b2  = (const float*)d_in[14];
  const float* Wfg = (const float*)d_in[15];
  const float* bfg = (const float*)d_in[16];
  const float* Embg= (const float*)d_in[17];
  const float* wg  = (const float*)d_in[18];

  int n = in_sizes[0] / 64;
  int E = in_sizes[2] / 2;

  char* base = (char*)d_ws;
  size_t off = 0;
  auto alloc = [&](size_t bytes) -> void* {
    void* p = base + off;
    off += bytes;
    off = (off + 255) & ~(size_t)255;
    return p;
  };
  int*   deg_i     = (int*)alloc((size_t)n * 4);
  int*   deg_dst   = (int*)alloc((size_t)n * 4);
  int*   cursor    = (int*)alloc((size_t)n * 4);
  size_t zero_bytes = off;                 // deg_i + deg_dst + cursor
  int*   row_start = (int*)alloc(((size_t)n + 1) * 4);
  int*   bsum      = (int*)alloc(1024 * 4);
  float* dinv      = (float*)alloc((size_t)n * 4);
  int*   srcs      = (int*)alloc((size_t)E * 4);
  float* coefs     = (float*)alloc((size_t)E * 4);
  float* CFG       = (float*)alloc((size_t)n * 3 * 4);
  unsigned* Xu     = (unsigned*)alloc((size_t)n * 80 * 4);   // bf16 X: 160 x 2B
  unsigned* Ztu    = (unsigned*)alloc((size_t)n * 80 * 4);   // bf16 Zt
  (void)ws_size;

  hipMemsetAsync(base, 0, zero_bytes, stream);

  int nb_scan = (n + 1023) / 1024;
  k_degrees<<<(E + 255) / 256, 256, 0, stream>>>(ei, E, deg_i, deg_dst);
  k_scan1<<<nb_scan, 1024, 0, stream>>>(deg_dst, n, bsum);
  k_scan2<<<1, 64, 0, stream>>>(bsum, nb_scan, row_start, n);
  k_scan3<<<nb_scan, 1024, 0, stream>>>(deg_dst, n, bsum, row_start, dinv);
  k_proj<<<(n + 63) / 64, 192, 0, stream>>>(feat, Wf0, bf0, Wf2, bf2, Wfg, bfg, wg, Xu, CFG, n);
  k_buildx<<<((size_t)n * 32 + 255) / 256, 256, 0, stream>>>(logits, deg_i, Emb1, Emb2, Xu, n);
  k_fill<<<(E + 255) / 256, 256, 0, stream>>>(ei, E, row_start, cursor, dinv, srcs, coefs);
  k_agg<<<(n + 3) / 4, 256, 0, stream>>>(Xu, Ztu, row_start, srcs, coefs, dinv, n);
  int waves = (n + 63) / 64;
  k_final<<<(waves + 3) / 4, 256, 0, stream>>>(Ztu, logits, CFG, deg_i, W0, b0, W1, b1, W2, b2,
                                               Embg, wg, (float*)d_out, n);
}

// Round 8
// 765.747 us; speedup vs baseline: 1.1070x; 1.1070x over previous
//
#include <hip/hip_runtime.h>
#include <hip/hip_bf16.h>
#include <math.h>

// GETS calibrator: MoE-GCN. N nodes, E edges, C=64, F=512, FH=32, DH=16.
// R8: k_proj replaced by k_projm (bf16 MFMA 16x16x32 for the [Wf0|Wf2] expert
//     part, double-buffered LDS, feat read ONCE) + fused fp32 CFG via the
//     reassociated precomputed Wv = Wfg @ wg_mid (k_wv). Gating stays fp32 ->
//     top-k decisions clean. R7's K-rotation reverted (K$ convoy was friendly).

#define XD 160   // aggregated feature dim
#define CC 64    // classes

typedef __attribute__((ext_vector_type(8))) short short8;
typedef __attribute__((ext_vector_type(4))) float f32x4;

static __device__ inline unsigned pk_bf16(float a, float b) {
  __hip_bfloat162 h;
  h.x = __float2bfloat16(a);
  h.y = __float2bfloat16(b);
  return *reinterpret_cast<unsigned*>(&h);
}
static __device__ inline unsigned short bf16u(float f) {
  __hip_bfloat16 h = __float2bfloat16(f);
  return *reinterpret_cast<unsigned short*>(&h);
}
static __device__ inline float bf_lo(unsigned u) {
  unsigned v = u << 16;
  return __builtin_bit_cast(float, v);
}
static __device__ inline float bf_hi(unsigned u) {
  unsigned v = u & 0xffff0000u;
  return __builtin_bit_cast(float, v);
}

// ---------------- degree counting ----------------
__global__ void k_degrees(const int* __restrict__ ei, int E,
                          int* __restrict__ deg_i, int* __restrict__ deg_dst) {
  int e = blockIdx.x * blockDim.x + threadIdx.x;
  if (e >= E) return;
  int s = ei[e], d = ei[E + e];
  atomicAdd(&deg_i[s], 1);
  atomicAdd(&deg_i[d], 1);
  atomicAdd(&deg_dst[d], 1);
}

// ---------------- 2-level exclusive scan of deg_dst -> row_start ----------------
__global__ void k_scan1(const int* __restrict__ deg, int n, int* __restrict__ bsum) {
  __shared__ int red[1024];
  int tid = threadIdx.x;
  int i = blockIdx.x * 1024 + tid;
  red[tid] = (i < n) ? deg[i] : 0;
  __syncthreads();
  for (int s = 512; s > 0; s >>= 1) {
    if (tid < s) red[tid] += red[tid + s];
    __syncthreads();
  }
  if (tid == 0) bsum[blockIdx.x] = red[0];
}

__global__ void k_scan2(int* __restrict__ bsum, int nb, int* __restrict__ row_start, int n) {
  if (threadIdx.x == 0 && blockIdx.x == 0) {
    int run = 0;
    for (int b = 0; b < nb; ++b) { int t = bsum[b]; bsum[b] = run; run += t; }
    row_start[n] = run;   // == E
  }
}

__global__ void k_scan3(const int* __restrict__ deg, int n, const int* __restrict__ bsum,
                        int* __restrict__ row_start, float* __restrict__ dinv) {
  __shared__ int sc[1024];
  int tid = threadIdx.x;
  int i = blockIdx.x * 1024 + tid;
  int v = (i < n) ? deg[i] : 0;
  sc[tid] = v;
  __syncthreads();
  for (int ofs = 1; ofs < 1024; ofs <<= 1) {
    int t = (tid >= ofs) ? sc[tid - ofs] : 0;
    __syncthreads();
    sc[tid] += t;
    __syncthreads();
  }
  if (i < n) {
    int incl = sc[tid];
    row_start[i] = incl - v + bsum[blockIdx.x];
    dinv[i] = rsqrtf((float)v + 1.0f);   // GCN deg = indeg + 1 (self loop)
  }
}

// ---------------- CSR fill (src + precomputed coef per edge) ----------------
__global__ void k_fill(const int* __restrict__ ei, int E, const int* __restrict__ row_start,
                       int* __restrict__ cursor, const float* __restrict__ dinv,
                       int* __restrict__ srcs, float* __restrict__ coefs) {
  int e = blockIdx.x * blockDim.x + threadIdx.x;
  if (e >= E) return;
  int s = ei[e], d = ei[E + e];
  int pos = row_start[d] + atomicAdd(&cursor[d], 1);
  srcs[pos] = s;
  coefs[pos] = dinv[s] * dinv[d];
}

// ---------------- Wv = Wfg(512x32) @ wg[64:96] (3 cols), fp32 ----------------
// Wv4[k] = float4(Wv[k][0..2], 0); row 512 = bfg @ wg_mid (the constant term).
__global__ void k_wv(const float* __restrict__ Wfg, const float* __restrict__ bfg,
                     const float* __restrict__ wg, float* __restrict__ Wv4) {
  int k = blockIdx.x * blockDim.x + threadIdx.x;
  if (k >= 512) return;
  float a0 = 0.f, a1 = 0.f, a2 = 0.f;
  for (int j = 0; j < 32; ++j) {
    float w = Wfg[k * 32 + j];
    a0 += w * wg[(64 + j) * 3 + 0];
    a1 += w * wg[(64 + j) * 3 + 1];
    a2 += w * wg[(64 + j) * 3 + 2];
  }
  float4 v; v.x = a0; v.y = a1; v.z = a2; v.w = 0.f;
  *(float4*)&Wv4[k * 4] = v;
  if (k == 0) {
    float c0 = 0.f, c1 = 0.f, c2 = 0.f;
    for (int j = 0; j < 32; ++j) {
      float b = bfg[j];
      c0 += b * wg[(64 + j) * 3 + 0];
      c1 += b * wg[(64 + j) * 3 + 1];
      c2 += b * wg[(64 + j) * 3 + 2];
    }
    float4 c; c.x = c0; c.y = c1; c.z = c2; c.w = 0.f;
    *(float4*)&Wv4[512 * 4] = c;
  }
}

// ---------------- k_projm: bf16 MFMA  feat(n,512) @ [Wf0|Wf2](512,64) + fp32 CFG -------
// Block: 64 nodes, 256 threads = 4 waves. Wave w computes rows w*16..w*16+15, all 64 cols.
// K-step 32, double-buffered LDS. CFG (fp32) accumulated during A-staging from the
// fp32 feat values (before bf16 conversion) against Wv4.
__global__ __launch_bounds__(256) void k_projm(
    const float* __restrict__ feat,
    const float* __restrict__ Wf0, const float* __restrict__ bf0,
    const float* __restrict__ Wf2, const float* __restrict__ bf2,
    const float* __restrict__ Wv4,
    unsigned* __restrict__ Xu, float* __restrict__ CFG, int n) {
  __shared__ unsigned short Al[2][64][40];    // [buf][node][k 0..31 bf16], 80B row (16B pad)
  __shared__ unsigned short Bs[2][4][64][8];  // [buf][ntile][lane][j] frag-ordered

  int t = threadIdx.x;
  int l = t & 63;
  int w = t >> 6;
  int blk = blockIdx.x;

  // staging roles
  int node_s = t >> 2;            // 0..63
  int kq = t & 3;                 // k-quarter within the 32-wide K-step
  int gn_s = blk * 64 + node_s;
  int gn_c = gn_s < n ? gn_s : n - 1;
  const float* frow = feat + (size_t)gn_c * 512 + kq * 8;

  // B staging role: thread (lane=l, ntile=w) provides lane l's frag of tile w
  int bk = (l >> 4) * 8;                    // k_local base
  int bc = (w << 4) + (l & 15);             // col 0..63
  const float* wsrc = (bc < 32) ? (Wf0 + bc) : (Wf2 + (bc - 32));

  float cfg0 = 0.f, cfg1 = 0.f, cfg2 = 0.f;

  auto stage = [&](int ks, int buf) {
    // ---- A tile + CFG ----
    float4 fa = *(const float4*)&frow[ks * 32];
    float4 fb = *(const float4*)&frow[ks * 32 + 4];
    float fv[8] = {fa.x, fa.y, fa.z, fa.w, fb.x, fb.y, fb.z, fb.w};
    const float* wv = Wv4 + (ks * 32 + kq * 8) * 4;
#pragma unroll
    for (int j = 0; j < 8; ++j) {
      float4 v = *(const float4*)&wv[j * 4];
      cfg0 += fv[j] * v.x;
      cfg1 += fv[j] * v.y;
      cfg2 += fv[j] * v.z;
    }
    unsigned short pa[8];
#pragma unroll
    for (int j = 0; j < 8; ++j) pa[j] = bf16u(fv[j]);
    *(uint4*)&Al[buf][node_s][kq * 8] = *(const uint4*)pa;
    // ---- B tile (L2-hot W re-read per block) ----
    unsigned short pb[8];
#pragma unroll
    for (int j = 0; j < 8; ++j)
      pb[j] = bf16u(wsrc[(size_t)(ks * 32 + bk + j) * 32]);
    *(uint4*)&Bs[buf][w][l][0] = *(const uint4*)pb;
  };

  f32x4 acc[4];
#pragma unroll
  for (int q = 0; q < 4; ++q) acc[q] = (f32x4){0.f, 0.f, 0.f, 0.f};

  stage(0, 0);
  int cur = 0;
  for (int ks = 0; ks < 16; ++ks) {
    __syncthreads();
    if (ks < 15) stage(ks + 1, cur ^ 1);
    short8 af = *(const short8*)&Al[cur][(w << 4) + (l & 15)][(l >> 4) * 8];
#pragma unroll
    for (int nt = 0; nt < 4; ++nt) {
      short8 bfv = *(const short8*)&Bs[cur][nt][l][0];
      acc[nt] = __builtin_amdgcn_mfma_f32_16x16x32_bf16(af, bfv, acc[nt], 0, 0, 0);
    }
    cur ^= 1;
  }

  // ---- CFG: reduce over the 4 k-quarter threads of each node ----
  cfg0 += __shfl_xor(cfg0, 1); cfg0 += __shfl_xor(cfg0, 2);
  cfg1 += __shfl_xor(cfg1, 1); cfg1 += __shfl_xor(cfg1, 2);
  cfg2 += __shfl_xor(cfg2, 1); cfg2 += __shfl_xor(cfg2, 2);
  if (kq == 0 && gn_s < n) {
    float4 cc = *(const float4*)&Wv4[512 * 4];
    CFG[gn_s] = cfg0 + cc.x;
    CFG[n + gn_s] = cfg1 + cc.y;
    CFG[2 * (size_t)n + gn_s] = cfg2 + cc.z;
  }

  // ---- store X (bf16): D[row=(l>>4)*4+r][col=nt*16+(l&15)] ----
  unsigned short* Xus = (unsigned short*)Xu;
#pragma unroll
  for (int nt = 0; nt < 4; ++nt) {
    int col = (nt << 4) + (l & 15);
    float bias = (col < 32) ? bf0[col] : bf2[col - 32];
    int fidx = (col < 32) ? (64 + col) : (80 + col);   // f0 -> 64..95, f2 -> 112..143
#pragma unroll
    for (int r = 0; r < 4; ++r) {
      int nd = blk * 64 + (w << 4) + ((l >> 4) << 2) + r;
      if (nd < n) Xus[(size_t)nd * 160 + fidx] = bf16u(acc[nt][r] + bias);
    }
  }
}

// ---------------- build X (bf16): logits copy + degree embeddings ----------------
__global__ void k_buildx(const float* __restrict__ logits, const int* __restrict__ deg_i,
                         const float* __restrict__ Emb1, const float* __restrict__ Emb2,
                         unsigned* __restrict__ Xu, int n) {
  int gid = blockIdx.x * blockDim.x + threadIdx.x;
  if (gid >= n * 32) return;
  int node = gid >> 5, p = gid & 31;
  unsigned* xr = Xu + (size_t)node * 80;
  const float* lgr = logits + (size_t)node * 64;
  float2 lg = *(const float2*)&lgr[2 * p];
  xr[p] = pk_bf16(lg.x, lg.y);          // features 0..63 -> uint 0..31
  if (p < 8) {
    int dg = deg_i[node]; if (dg > 127) dg = 127;
    float2 e1 = *(const float2*)&Emb1[dg * 16 + 2 * p];
    float2 e2 = *(const float2*)&Emb2[dg * 16 + 2 * p];
    xr[48 + p] = pk_bf16(e1.x, e1.y);   // features 96..111
    xr[72 + p] = pk_bf16(e2.x, e2.y);   // features 144..159
  }
}

// ---------------- aggregation: Zt(bf16) = A_hat @ X(bf16), chunk-major ----------------
__global__ __launch_bounds__(256) void k_agg(
    const unsigned* __restrict__ Xu, unsigned* __restrict__ Ztu,
    const int* __restrict__ row_start, const int* __restrict__ srcs,
    const float* __restrict__ coefs, const float* __restrict__ dinv, int n) {
  int w = threadIdx.x >> 6, l = threadIdx.x & 63;
  int node = blockIdx.x * 4 + w;
  if (node >= n) return;
  int beg = row_start[node], end = row_start[node + 1];
  float ax = 0.f, ay = 0.f, bx = 0.f, by = 0.f;
  for (int i = beg; i < end; ++i) {
    int s = srcs[i];
    float c = coefs[i];
    const unsigned* xr = Xu + (size_t)s * 80;
    unsigned u = xr[l];
    ax += c * bf_lo(u);
    ay += c * bf_hi(u);
    if (l < 16) {
      unsigned u2 = xr[64 + l];
      bx += c * bf_lo(u2);
      by += c * bf_hi(u2);
    }
  }
  float di = dinv[node];
  float c2 = di * di;
  const unsigned* xs = Xu + (size_t)node * 80;
  {
    unsigned u = xs[l];
    ax += c2 * bf_lo(u);
    ay += c2 * bf_hi(u);
    if (l < 16) {
      unsigned u2 = xs[64 + l];
      bx += c2 * bf_lo(u2);
      by += c2 * bf_hi(u2);
    }
  }
  Ztu[2 * ((size_t)(l >> 1) * n + node) + (l & 1)] = pk_bf16(ax, ay);
  if (l < 16)
    Ztu[2 * ((size_t)(32 + (l >> 1)) * n + node) + (l & 1)] = pk_bf16(bx, by);
}

// ---------------- final: lane=node, W via uniform scalar loads, comb[64] in VGPRs ---------
__global__ __launch_bounds__(256, 4) void k_final(
    const unsigned* __restrict__ Ztu, const float* __restrict__ logits,
    const float* __restrict__ CFG, const int* __restrict__ deg_i,
    const float* __restrict__ W0, const float* __restrict__ b0,
    const float* __restrict__ W1, const float* __restrict__ b1,
    const float* __restrict__ W2, const float* __restrict__ b2,
    const float* __restrict__ Embg, const float* __restrict__ wg,
    float* __restrict__ out, int n) {
  int l = threadIdx.x & 63;
  int w = threadIdx.x >> 6;
  int g = blockIdx.x * 4 + w;
  int node = g * 64 + l;
  int nc = node < n ? node : n - 1;

  // ---- gating (fp32): logits part + Embg part + folded FG part ----
  float c0 = 0.f, c1 = 0.f, c2 = 0.f;
  const float* lgr = logits + (size_t)nc * 64;
#pragma unroll
  for (int q = 0; q < 16; ++q) {
    float4 v = *(const float4*)&lgr[q * 4];
    const float* p = (const float*)&v;
#pragma unroll
    for (int j = 0; j < 4; ++j) {
      int k = q * 4 + j;
      c0 += p[j] * wg[k * 3 + 0];
      c1 += p[j] * wg[k * 3 + 1];
      c2 += p[j] * wg[k * 3 + 2];
    }
  }
  {
    int dg = deg_i[nc]; if (dg > 127) dg = 127;
    const float* egr = Embg + dg * 16;
#pragma unroll
    for (int q = 0; q < 4; ++q) {
      float4 v = *(const float4*)&egr[q * 4];
      const float* p = (const float*)&v;
#pragma unroll
      for (int j = 0; j < 4; ++j) {
        int k = 96 + q * 4 + j;
        c0 += p[j] * wg[k * 3 + 0];
        c1 += p[j] * wg[k * 3 + 1];
        c2 += p[j] * wg[k * 3 + 2];
      }
    }
  }
  c0 += CFG[nc];
  c1 += CFG[n + nc];
  c2 += CFG[2 * (size_t)n + nc];

  int i0 = 0; float t0 = c0;
  if (c1 > t0) { t0 = c1; i0 = 1; }
  if (c2 > t0) { t0 = c2; i0 = 2; }
  float t1 = -3.4e38f; int i1 = 0;
  if (i0 != 0) { t1 = c0; i1 = 0; }
  if (i0 != 1 && c1 > t1) { t1 = c1; i1 = 1; }
  if (i0 != 2 && c2 > t1) { t1 = c2; i1 = 2; }
  float e1v = expf(t1 - t0);
  float gsum = 1.0f + e1v;
  float gA = 1.0f / gsum, gB = e1v / gsum;
  float g0 = (i0 == 0) ? gA : (i1 == 0) ? gB : 0.f;
  float g1 = (i0 == 1) ? gA : (i1 == 1) ? gB : 0.f;
  float g2 = (i0 == 2) ? gA : (i1 == 2) ? gB : 0.f;

  float comb[64];
#pragma unroll
  for (int c = 0; c < 64; ++c) comb[c] = 0.f;

#define CHUNK(CIDX, GE, WPTR, KROW)                                        \
  {                                                                        \
    uint2 zu = *(const uint2*)&Ztu[2 * ((size_t)(CIDX) * n + nc)];         \
    float zs[4] = {(GE) * bf_lo(zu.x), (GE) * bf_hi(zu.x),                 \
                   (GE) * bf_lo(zu.y), (GE) * bf_hi(zu.y)};                \
    const float* wr = (WPTR) + (KROW) * 64;                                \
    _Pragma("unroll") for (int kk = 0; kk < 4; ++kk) {                     \
      float zz = zs[kk];                                                   \
      const float* wrow = wr + kk * 64;                                    \
      _Pragma("unroll") for (int c = 0; c < 64; ++c)                       \
        comb[c] += zz * wrow[c];                                           \
    }                                                                      \
  }

  for (int t = 0; t < 24; ++t) CHUNK(t, g0, W0, 4 * t);
  for (int t = 0; t < 16; ++t) CHUNK(t, g1, W1, 4 * t);
  for (int t = 0; t < 4; ++t)  CHUNK(24 + t, g1, W1, 64 + 4 * t);
  for (int t = 0; t < 12; ++t) CHUNK(28 + t, g2, W2, 4 * t);
#undef CHUNK

#pragma unroll
  for (int c = 0; c < 64; ++c)
    comb[c] += g0 * b0[c] + g1 * b1[c] + g2 * b2[c];

  if (node < n) {
    float4* outr = (float4*)(out + (size_t)node * 64);
#pragma unroll
    for (int q = 0; q < 16; ++q) {
      float4 lg4 = *(const float4*)&lgr[q * 4];
      const float* pl = (const float*)&lg4;
      float4 o;
      float* po = (float*)&o;
#pragma unroll
      for (int j = 0; j < 4; ++j) {
        float v = comb[q * 4 + j];
        float sp = fmaxf(v, 0.f) + log1pf(expf(-fabsf(v)));
        po[j] = pl[j] * sp;
      }
      outr[q] = o;
    }
  }
}

extern "C" void kernel_launch(void* const* d_in, const int* in_sizes, int n_in,
                              void* d_out, int out_size, void* d_ws, size_t ws_size,
                              hipStream_t stream) {
  const float* logits = (const float*)d_in[0];
  const float* feat   = (const float*)d_in[1];
  const int*   ei     = (const int*)d_in[2];
  const float* Wf0 = (const float*)d_in[3];
  const float* bf0 = (const float*)d_in[4];
  const float* W0  = (const float*)d_in[5];
  const float* b0  = (const float*)d_in[6];
  const float* Emb1= (const float*)d_in[7];
  const float* W1  = (const float*)d_in[8];
  const float* b1  = (const float*)d_in[9];
  const float* Wf2 = (const float*)d_in[10];
  const float* bf2 = (const float*)d_in[11];
  const float* Emb2= (const float*)d_in[12];
  const float* W2  = (const float*)d_in[13];
  const float* b2  = (const float*)d_in[14];
  const float* Wfg = (const float*)d_in[15];
  const float* bfg = (const float*)d_in[16];
  const float* Embg= (const float*)d_in[17];
  const float* wg  = (const float*)d_in[18];

  int n = in_sizes[0] / 64;
  int E = in_sizes[2] / 2;

  char* base = (char*)d_ws;
  size_t off = 0;
  auto alloc = [&](size_t bytes) -> void* {
    void* p = base + off;
    off += bytes;
    off = (off + 255) & ~(size_t)255;
    return p;
  };
  int*   deg_i     = (int*)alloc((size_t)n * 4);
  int*   deg_dst   = (int*)alloc((size_t)n * 4);
  int*   cursor    = (int*)alloc((size_t)n * 4);
  size_t zero_bytes = off;                 // deg_i + deg_dst + cursor
  int*   row_start = (int*)alloc(((size_t)n + 1) * 4);
  int*   bsum      = (int*)alloc(1024 * 4);
  float* dinv      = (float*)alloc((size_t)n * 4);
  int*   srcs      = (int*)alloc((size_t)E * 4);
  float* coefs     = (float*)alloc((size_t)E * 4);
  float* CFG       = (float*)alloc((size_t)n * 3 * 4);
  float* Wv4       = (float*)alloc((size_t)513 * 4 * 4);
  unsigned* Xu     = (unsigned*)alloc((size_t)n * 80 * 4);   // bf16 X: 160 x 2B
  unsigned* Ztu    = (unsigned*)alloc((size_t)n * 80 * 4);   // bf16 Zt
  (void)ws_size;

  hipMemsetAsync(base, 0, zero_bytes, stream);

  int nb_scan = (n + 1023) / 1024;
  k_degrees<<<(E + 255) / 256, 256, 0, stream>>>(ei, E, deg_i, deg_dst);
  k_scan1<<<nb_scan, 1024, 0, stream>>>(deg_dst, n, bsum);
  k_scan2<<<1, 64, 0, stream>>>(bsum, nb_scan, row_start, n);
  k_scan3<<<nb_scan, 1024, 0, stream>>>(deg_dst, n, bsum, row_start, dinv);
  k_wv<<<2, 256, 0, stream>>>(Wfg, bfg, wg, Wv4);
  k_projm<<<(n + 63) / 64, 256, 0, stream>>>(feat, Wf0, bf0, Wf2, bf2, Wv4, Xu, CFG, n);
  k_buildx<<<((size_t)n * 32 + 255) / 256, 256, 0, stream>>>(logits, deg_i, Emb1, Emb2, Xu, n);
  k_fill<<<(E + 255) / 256, 256, 0, stream>>>(ei, E, row_start, cursor, dinv, srcs, coefs);
  k_agg<<<(n + 3) / 4, 256, 0, stream>>>(Xu, Ztu, row_start, srcs, coefs, dinv, n);
  int waves = (n + 63) / 64;
  k_final<<<(waves + 3) / 4, 256, 0, stream>>>(Ztu, logits, CFG, deg_i, W0, b0, W1, b1, W2, b2,
                                               Embg, wg, (float*)d_out, n);
}